// Round 1
// baseline (1094.377 us; speedup 1.0000x reference)
//
#include <hip/hip_runtime.h>
#include <hip/hip_bf16.h>
#include <stdint.h>

// ============================================================================
// MinGRU (2 layers), B=8 S=4096 D=H=1024.
// Pipeline:
//   1. x (f32) -> bf16
//   2. GEMM0: gh = x_bf16 @ W0^T + b0   (M=32768,N=2048,K=1024, f32 out)
//   3. scan0: fused sigmoid/g + chunked linear scan -> h1 (bf16)
//   4. GEMM1: gh = h1 @ W1^T + b1
//   5. scan1: -> out (f32)
// Scan identity: log-space reference == h_t = (1-z)h_{t-1} + z*g(h~), h0=0.5.
// ============================================================================

typedef __attribute__((ext_vector_type(8))) short bf16x8;   // 8 bf16 = 4 VGPRs
typedef __attribute__((ext_vector_type(4))) float f32x4;

__device__ __forceinline__ unsigned short f2bf(float f) {
    union { float f; unsigned int u; } x; x.f = f;
    unsigned int r = x.u + 0x7fffu + ((x.u >> 16) & 1u);   // RNE
    return (unsigned short)(r >> 16);
}

__device__ __forceinline__ float sigmoidf_(float x) {
    return 1.0f / (1.0f + __expf(-x));
}

// ---------------------------------------------------------------------------
// f32 -> bf16, 8 elems/thread (16B in / 16B out... 32B in, 16B out)
// ---------------------------------------------------------------------------
__global__ void f32_to_bf16_k(const float* __restrict__ in,
                              unsigned short* __restrict__ out, int n8) {
    int i = blockIdx.x * blockDim.x + threadIdx.x;
    if (i >= n8) return;
    const float4* p = reinterpret_cast<const float4*>(in);
    float4 a = p[2 * i], b = p[2 * i + 1];
    float f[8] = {a.x, a.y, a.z, a.w, b.x, b.y, b.z, b.w};
    union { unsigned short s[8]; uint4 v; } u;
#pragma unroll
    for (int j = 0; j < 8; ++j) u.s[j] = f2bf(f[j]);
    *reinterpret_cast<uint4*>(out + (size_t)i * 8) = u.v;
}

// ---------------------------------------------------------------------------
// GEMM: C[m,n] = sum_k A[m,k]*Wt[n,k] + bias[n].  A:(M,K) bf16, Wt:(N,K) bf16.
// 128x128 tile, BK=64, 4 waves (2x2), each wave 4x4 MFMA tiles of 16x16x32.
// LDS layout = fragment order: 1KB block per (tile,kc), lane L holds
// src[row=t*16+(L&15)][kc*32+(L>>4)*8 .. +8] -> all ds traffic contiguous.
// ---------------------------------------------------------------------------
__global__ __launch_bounds__(256) void gemm_bt(
    const short* __restrict__ A, const short* __restrict__ Wt,
    const float* __restrict__ bias, float* __restrict__ C,
    int M, int N, int K)
{
    __shared__ __align__(16) short lds_a[8192];   // 16KB
    __shared__ __align__(16) short lds_b[8192];   // 16KB

    const int tid  = threadIdx.x;
    const int lane = tid & 63;
    const int wave = tid >> 6;
    const int wm   = wave >> 1;            // 0..1
    const int wn   = wave & 1;             // 0..1
    const int m0   = blockIdx.x * 128;
    const int n0   = blockIdx.y * 128;

    f32x4 acc[4][4] = {};

    // staging addresses (chunk c = tid + 256*i; block=c>>6, L=c&63)
    const short* ga[4]; const short* gw[4]; uint4* sa[4]; uint4* sb[4];
#pragma unroll
    for (int i = 0; i < 4; ++i) {
        int c   = tid + i * 256;
        int blk = c >> 6;
        int L   = c & 63;
        int row = (blk >> 1) * 16 + (L & 15);
        int col = (blk & 1) * 32 + ((L >> 4) * 8);
        ga[i] = A  + (size_t)(m0 + row) * K + col;
        gw[i] = Wt + (size_t)(n0 + row) * K + col;
        sa[i] = reinterpret_cast<uint4*>(lds_a + c * 8);
        sb[i] = reinterpret_cast<uint4*>(lds_b + c * 8);
    }

    for (int k0 = 0; k0 < K; k0 += 64) {
#pragma unroll
        for (int i = 0; i < 4; ++i) {
            *sa[i] = *reinterpret_cast<const uint4*>(ga[i] + k0);
            *sb[i] = *reinterpret_cast<const uint4*>(gw[i] + k0);
        }
        __syncthreads();
#pragma unroll
        for (int kc = 0; kc < 2; ++kc) {
            bf16x8 af[4], bf[4];
#pragma unroll
            for (int t = 0; t < 4; ++t) {
                int tma = wm * 4 + t;
                int tnb = wn * 4 + t;
                af[t] = *reinterpret_cast<const bf16x8*>(lds_a + ((tma * 2 + kc) * 64 + lane) * 8);
                bf[t] = *reinterpret_cast<const bf16x8*>(lds_b + ((tnb * 2 + kc) * 64 + lane) * 8);
            }
#pragma unroll
            for (int tm = 0; tm < 4; ++tm)
#pragma unroll
                for (int tn = 0; tn < 4; ++tn)
                    acc[tm][tn] = __builtin_amdgcn_mfma_f32_16x16x32_bf16(
                        af[tm], bf[tn], acc[tm][tn], 0, 0, 0);
        }
        __syncthreads();
    }

    // epilogue: C/D layout (measured m89/m91): col=lane&15, row=quad*4+reg
    const int quad = lane >> 4;
    const int lcol = lane & 15;
#pragma unroll
    for (int tm = 0; tm < 4; ++tm) {
        int mrow = m0 + wm * 64 + tm * 16 + quad * 4;
#pragma unroll
        for (int tn = 0; tn < 4; ++tn) {
            int ecol = n0 + wn * 64 + tn * 16 + lcol;
            float bv = bias[ecol];
#pragma unroll
            for (int r = 0; r < 4; ++r)
                C[(size_t)(mrow + r) * N + ecol] = acc[tm][tn][r] + bv;
        }
    }
}

// ---------------------------------------------------------------------------
// Chunked scan. gh:(B*S, 2048) f32, gate=cols[0,1024), hidden=[1024,2048).
// 64 chunks of 64 steps. channel ch = b*1024 + h (8192 total).
// ---------------------------------------------------------------------------
__global__ void scan_partial(const float* __restrict__ gh,
                             float* __restrict__ P, float* __restrict__ V) {
    const int h = blockIdx.x * blockDim.x + threadIdx.x;  // 0..1023
    const int j = blockIdx.y;                             // chunk
    const int b = blockIdx.z;
    const size_t base = ((size_t)b * 4096 + (size_t)j * 64) * 2048 + h;
    float p = 1.0f, hl = 0.0f;
#pragma unroll 8
    for (int t = 0; t < 64; ++t) {
        float g  = gh[base + (size_t)t * 2048];
        float hd = gh[base + (size_t)t * 2048 + 1024];
        float z  = sigmoidf_(g);
        float c  = 1.0f - z;
        float gv = (hd >= 0.0f) ? (hd + 0.5f) : sigmoidf_(hd);
        p  = p * c;
        hl = c * hl + z * gv;
    }
    const int ch = b * 1024 + h;
    P[j * 8192 + ch] = p;
    V[j * 8192 + ch] = hl;
}

__global__ void scan_combine(const float* __restrict__ P,
                             const float* __restrict__ V,
                             float* __restrict__ hstart) {
    const int ch = blockIdx.x * blockDim.x + threadIdx.x;  // 0..8191
    float h = 0.5f;   // h0 = g(0) = 0.5
#pragma unroll 8
    for (int j = 0; j < 64; ++j) {
        hstart[j * 8192 + ch] = h;
        h = P[j * 8192 + ch] * h + V[j * 8192 + ch];
    }
}

__device__ __forceinline__ void store_out(float* p, float v) { *p = v; }
__device__ __forceinline__ void store_out(unsigned short* p, float v) { *p = f2bf(v); }

template <typename OUT>
__global__ void scan_final(const float* __restrict__ gh,
                           const float* __restrict__ hstart,
                           OUT* __restrict__ out) {
    const int h = blockIdx.x * blockDim.x + threadIdx.x;
    const int j = blockIdx.y;
    const int b = blockIdx.z;
    const size_t base  = ((size_t)b * 4096 + (size_t)j * 64) * 2048 + h;
    const size_t obase = ((size_t)b * 4096 + (size_t)j * 64) * 1024 + h;
    float hv = hstart[j * 8192 + b * 1024 + h];
#pragma unroll 8
    for (int t = 0; t < 64; ++t) {
        float g  = gh[base + (size_t)t * 2048];
        float hd = gh[base + (size_t)t * 2048 + 1024];
        float z  = sigmoidf_(g);
        float c  = 1.0f - z;
        float gv = (hd >= 0.0f) ? (hd + 0.5f) : sigmoidf_(hd);
        hv = c * hv + z * gv;
        store_out(out + obase + (size_t)t * 1024, hv);
    }
}

// ---------------------------------------------------------------------------
extern "C" void kernel_launch(void* const* d_in, const int* in_sizes, int n_in,
                              void* d_out, int out_size, void* d_ws, size_t ws_size,
                              hipStream_t stream) {
    const float* x  = (const float*)d_in[0];   // (8,4096,1024)
    const float* W0 = (const float*)d_in[1];   // (2048,1024)
    const float* b0 = (const float*)d_in[2];   // (2048,)
    const float* W1 = (const float*)d_in[3];   // (2048,1024)
    const float* b1 = (const float*)d_in[4];   // (2048,)
    float* out = (float*)d_out;                // (8,4096,1024) f32

    char* ws = (char*)d_ws;
    // workspace map (total ~334MB)
    float*          gh   = (float*)ws;                                  // 256MB
    unsigned short* abuf = (unsigned short*)(ws + 268435456);           // 64MB: x_bf16, later h1_bf16
    unsigned short* w0b  = (unsigned short*)(ws + 335544320);           // 4MB
    unsigned short* w1b  = (unsigned short*)(ws + 339738624);           // 4MB
    float*          P    = (float*)(ws + 343932928);                    // 2MB
    float*          V    = (float*)(ws + 346030080);                    // 2MB
    float*          hst  = (float*)(ws + 348127232);                    // 2MB

    const int M = 32768, N = 2048, K = 1024;

    f32_to_bf16_k<<<4194304 / 256, 256, 0, stream>>>(x,  abuf, 4194304);
    f32_to_bf16_k<<<262144 / 256, 256, 0, stream>>>(W0, w0b, 262144);
    f32_to_bf16_k<<<262144 / 256, 256, 0, stream>>>(W1, w1b, 262144);

    dim3 gg(M / 128, N / 128);   // (256,16)
    dim3 sg(4, 64, 8);           // (h-blocks, chunks, batch)

    // layer 0
    gemm_bt<<<gg, 256, 0, stream>>>((const short*)abuf, (const short*)w0b, b0, gh, M, N, K);
    scan_partial<<<sg, 256, 0, stream>>>(gh, P, V);
    scan_combine<<<32, 256, 0, stream>>>(P, V, hst);
    scan_final<unsigned short><<<sg, 256, 0, stream>>>(gh, hst, abuf);  // h1 -> bf16

    // layer 1
    gemm_bt<<<gg, 256, 0, stream>>>((const short*)abuf, (const short*)w1b, b1, gh, M, N, K);
    scan_partial<<<sg, 256, 0, stream>>>(gh, P, V);
    scan_combine<<<32, 256, 0, stream>>>(P, V, hst);
    scan_final<float><<<sg, 256, 0, stream>>>(gh, hst, out);
}

// Round 2
// 1086.472 us; speedup vs baseline: 1.0073x; 1.0073x over previous
//
#include <hip/hip_runtime.h>
#include <hip/hip_bf16.h>
#include <stdint.h>

// ============================================================================
// MinGRU (2 layers), B=8 S=4096 D=H=1024.
// Pipeline:
//   1. x (f32) -> bf16
//   2. GEMM0: gh = x_bf16 @ W0^T + b0   (M=32768,N=2048,K=1024, f32 out)
//   3. scan0: fused sigmoid/g + chunked linear scan -> h1 (bf16)
//   4. GEMM1: gh = h1 @ W1^T + b1
//   5. scan1: -> out (f32)
// Scan identity: log-space reference == h_t = (1-z)h_{t-1} + z*g(h~), h0=0.5.
// R2 change: GEMM staging via global_load_lds width=16 (ladder step 3, m97).
// ============================================================================

typedef __attribute__((ext_vector_type(8))) short bf16x8;   // 8 bf16 = 4 VGPRs
typedef __attribute__((ext_vector_type(4))) float f32x4;

__device__ __forceinline__ unsigned short f2bf(float f) {
    union { float f; unsigned int u; } x; x.f = f;
    unsigned int r = x.u + 0x7fffu + ((x.u >> 16) & 1u);   // RNE
    return (unsigned short)(r >> 16);
}

__device__ __forceinline__ float sigmoidf_(float x) {
    return 1.0f / (1.0f + __expf(-x));
}

// async 16B/lane global->LDS. lds must be wave-uniform; HW dest = lds + lane*16.
__device__ __forceinline__ void async_cp16(const void* g, void* lds) {
    __builtin_amdgcn_global_load_lds(
        (const __attribute__((address_space(1))) unsigned int*)g,
        (__attribute__((address_space(3))) unsigned int*)lds, 16, 0, 0);
}

// ---------------------------------------------------------------------------
// f32 -> bf16, 8 elems/thread
// ---------------------------------------------------------------------------
__global__ void f32_to_bf16_k(const float* __restrict__ in,
                              unsigned short* __restrict__ out, int n8) {
    int i = blockIdx.x * blockDim.x + threadIdx.x;
    if (i >= n8) return;
    const float4* p = reinterpret_cast<const float4*>(in);
    float4 a = p[2 * i], b = p[2 * i + 1];
    float f[8] = {a.x, a.y, a.z, a.w, b.x, b.y, b.z, b.w};
    union { unsigned short s[8]; uint4 v; } u;
#pragma unroll
    for (int j = 0; j < 8; ++j) u.s[j] = f2bf(f[j]);
    *reinterpret_cast<uint4*>(out + (size_t)i * 8) = u.v;
}

// ---------------------------------------------------------------------------
// GEMM: C[m,n] = sum_k A[m,k]*Wt[n,k] + bias[n].  A:(M,K) bf16, Wt:(N,K) bf16.
// 128x128 tile, BK=64, 4 waves (2x2), each wave 4x4 MFMA tiles of 16x16x32.
// LDS layout = fragment order: 1KB block per (tile,kc); chunk c = wave*64 +
// i*256 + lane sits at lds + c*16B = (wave-uniform base) + lane*16B, which is
// exactly global_load_lds_dwordx4's addressing form.
// ---------------------------------------------------------------------------
__global__ __launch_bounds__(256) void gemm_bt(
    const short* __restrict__ A, const short* __restrict__ Wt,
    const float* __restrict__ bias, float* __restrict__ C,
    int M, int N, int K)
{
    __shared__ __align__(16) short lds_a[8192];   // 16KB
    __shared__ __align__(16) short lds_b[8192];   // 16KB

    const int tid  = threadIdx.x;
    const int lane = tid & 63;
    const int wave = tid >> 6;
    const int wm   = wave >> 1;            // 0..1
    const int wn   = wave & 1;             // 0..1
    const int m0   = blockIdx.x * 128;
    const int n0   = blockIdx.y * 128;

    f32x4 acc[4][4] = {};

    // staging addresses: chunk c = wave*64 + i*256 + lane
    const short* ga[4]; const short* gw[4];
    short* la[4]; short* lb[4];   // wave-uniform LDS bases
#pragma unroll
    for (int i = 0; i < 4; ++i) {
        int c   = tid + i * 256;               // = wave*64 + lane + i*256
        int blk = c >> 6;
        int L   = c & 63;
        int row = (blk >> 1) * 16 + (L & 15);
        int col = (blk & 1) * 32 + ((L >> 4) * 8);
        ga[i] = A  + (size_t)(m0 + row) * K + col;
        gw[i] = Wt + (size_t)(n0 + row) * K + col;
        int cbase = (wave * 64 + i * 256) * 8;  // shorts; lane offset is implicit
        la[i] = lds_a + cbase;
        lb[i] = lds_b + cbase;
    }

    for (int k0 = 0; k0 < K; k0 += 64) {
#pragma unroll
        for (int i = 0; i < 4; ++i) {
            async_cp16(ga[i] + k0, la[i]);
            async_cp16(gw[i] + k0, lb[i]);
        }
        __syncthreads();   // drains vmcnt -> LDS tiles complete
#pragma unroll
        for (int kc = 0; kc < 2; ++kc) {
            bf16x8 af[4], bf[4];
#pragma unroll
            for (int t = 0; t < 4; ++t) {
                int tma = wm * 4 + t;
                int tnb = wn * 4 + t;
                af[t] = *reinterpret_cast<const bf16x8*>(lds_a + ((tma * 2 + kc) * 64 + lane) * 8);
                bf[t] = *reinterpret_cast<const bf16x8*>(lds_b + ((tnb * 2 + kc) * 64 + lane) * 8);
            }
#pragma unroll
            for (int tm = 0; tm < 4; ++tm)
#pragma unroll
                for (int tn = 0; tn < 4; ++tn)
                    acc[tm][tn] = __builtin_amdgcn_mfma_f32_16x16x32_bf16(
                        af[tm], bf[tn], acc[tm][tn], 0, 0, 0);
        }
        __syncthreads();
    }

    // epilogue: C/D layout (measured m89/m91): col=lane&15, row=quad*4+reg
    const int quad = lane >> 4;
    const int lcol = lane & 15;
#pragma unroll
    for (int tm = 0; tm < 4; ++tm) {
        int mrow = m0 + wm * 64 + tm * 16 + quad * 4;
#pragma unroll
        for (int tn = 0; tn < 4; ++tn) {
            int ecol = n0 + wn * 64 + tn * 16 + lcol;
            float bv = bias[ecol];
#pragma unroll
            for (int r = 0; r < 4; ++r)
                C[(size_t)(mrow + r) * N + ecol] = acc[tm][tn][r] + bv;
        }
    }
}

// ---------------------------------------------------------------------------
// Chunked scan. gh:(B*S, 2048) f32, gate=cols[0,1024), hidden=[1024,2048).
// 64 chunks of 64 steps. channel ch = b*1024 + h (8192 total).
// ---------------------------------------------------------------------------
__global__ void scan_partial(const float* __restrict__ gh,
                             float* __restrict__ P, float* __restrict__ V) {
    const int h = blockIdx.x * blockDim.x + threadIdx.x;  // 0..1023
    const int j = blockIdx.y;                             // chunk
    const int b = blockIdx.z;
    const size_t base = ((size_t)b * 4096 + (size_t)j * 64) * 2048 + h;
    float p = 1.0f, hl = 0.0f;
#pragma unroll 8
    for (int t = 0; t < 64; ++t) {
        float g  = gh[base + (size_t)t * 2048];
        float hd = gh[base + (size_t)t * 2048 + 1024];
        float z  = sigmoidf_(g);
        float c  = 1.0f - z;
        float gv = (hd >= 0.0f) ? (hd + 0.5f) : sigmoidf_(hd);
        p  = p * c;
        hl = c * hl + z * gv;
    }
    const int ch = b * 1024 + h;
    P[j * 8192 + ch] = p;
    V[j * 8192 + ch] = hl;
}

__global__ void scan_combine(const float* __restrict__ P,
                             const float* __restrict__ V,
                             float* __restrict__ hstart) {
    const int ch = blockIdx.x * blockDim.x + threadIdx.x;  // 0..8191
    float h = 0.5f;   // h0 = g(0) = 0.5
#pragma unroll 8
    for (int j = 0; j < 64; ++j) {
        hstart[j * 8192 + ch] = h;
        h = P[j * 8192 + ch] * h + V[j * 8192 + ch];
    }
}

__device__ __forceinline__ void store_out(float* p, float v) { *p = v; }
__device__ __forceinline__ void store_out(unsigned short* p, float v) { *p = f2bf(v); }

template <typename OUT>
__global__ void scan_final(const float* __restrict__ gh,
                           const float* __restrict__ hstart,
                           OUT* __restrict__ out) {
    const int h = blockIdx.x * blockDim.x + threadIdx.x;
    const int j = blockIdx.y;
    const int b = blockIdx.z;
    const size_t base  = ((size_t)b * 4096 + (size_t)j * 64) * 2048 + h;
    const size_t obase = ((size_t)b * 4096 + (size_t)j * 64) * 1024 + h;
    float hv = hstart[j * 8192 + b * 1024 + h];
#pragma unroll 8
    for (int t = 0; t < 64; ++t) {
        float g  = gh[base + (size_t)t * 2048];
        float hd = gh[base + (size_t)t * 2048 + 1024];
        float z  = sigmoidf_(g);
        float c  = 1.0f - z;
        float gv = (hd >= 0.0f) ? (hd + 0.5f) : sigmoidf_(hd);
        hv = c * hv + z * gv;
        store_out(out + obase + (size_t)t * 1024, hv);
    }
}

// ---------------------------------------------------------------------------
extern "C" void kernel_launch(void* const* d_in, const int* in_sizes, int n_in,
                              void* d_out, int out_size, void* d_ws, size_t ws_size,
                              hipStream_t stream) {
    const float* x  = (const float*)d_in[0];   // (8,4096,1024)
    const float* W0 = (const float*)d_in[1];   // (2048,1024)
    const float* b0 = (const float*)d_in[2];   // (2048,)
    const float* W1 = (const float*)d_in[3];   // (2048,1024)
    const float* b1 = (const float*)d_in[4];   // (2048,)
    float* out = (float*)d_out;                // (8,4096,1024) f32

    char* ws = (char*)d_ws;
    // workspace map (total ~334MB)
    float*          gh   = (float*)ws;                                  // 256MB
    unsigned short* abuf = (unsigned short*)(ws + 268435456);           // 64MB: x_bf16, later h1_bf16
    unsigned short* w0b  = (unsigned short*)(ws + 335544320);           // 4MB
    unsigned short* w1b  = (unsigned short*)(ws + 339738624);           // 4MB
    float*          P    = (float*)(ws + 343932928);                    // 2MB
    float*          V    = (float*)(ws + 346030080);                    // 2MB
    float*          hst  = (float*)(ws + 348127232);                    // 2MB

    const int M = 32768, N = 2048, K = 1024;

    f32_to_bf16_k<<<4194304 / 256, 256, 0, stream>>>(x,  abuf, 4194304);
    f32_to_bf16_k<<<262144 / 256, 256, 0, stream>>>(W0, w0b, 262144);
    f32_to_bf16_k<<<262144 / 256, 256, 0, stream>>>(W1, w1b, 262144);

    dim3 gg(M / 128, N / 128);   // (256,16)
    dim3 sg(4, 64, 8);           // (h-blocks, chunks, batch)

    // layer 0
    gemm_bt<<<gg, 256, 0, stream>>>((const short*)abuf, (const short*)w0b, b0, gh, M, N, K);
    scan_partial<<<sg, 256, 0, stream>>>(gh, P, V);
    scan_combine<<<32, 256, 0, stream>>>(P, V, hst);
    scan_final<unsigned short><<<sg, 256, 0, stream>>>(gh, hst, abuf);  // h1 -> bf16

    // layer 1
    gemm_bt<<<gg, 256, 0, stream>>>((const short*)abuf, (const short*)w1b, b1, gh, M, N, K);
    scan_partial<<<sg, 256, 0, stream>>>(gh, P, V);
    scan_combine<<<32, 256, 0, stream>>>(P, V, hst);
    scan_final<float><<<sg, 256, 0, stream>>>(gh, hst, out);
}